// Round 1
// baseline (67.076 us; speedup 1.0000x reference)
//
#include <hip/hip_runtime.h>

#define CH 64
#define NN 56
#define RPB 14            // output rows per block
#define TR  16            // t4 rows computed per block (RPB + 2)
#define XSTRIDE (NN*NN)   // 3136 floats per channel image

// Fused: t4 = conv1d(x; w2) over channels (K=3, pad 1, along last axis),
//        out[i,m,l] = w1[i,0]*t4[i,(m-1)%56,l] + w1[i,1]*t4[i,(m-2)%56,l]
__global__ __launch_bounds__(1024, 1) void fused_shift_conv(
    const float* __restrict__ x,
    const float* __restrict__ w1,
    const float* __restrict__ w2,
    float* __restrict__ out)
{
    __shared__ float w2s[CH * 3];        // weights for this block's channel i
    __shared__ float t4s[TR][NN];        // 16 x 56 conv rows

    const int i  = blockIdx.x >> 2;      // output channel 0..63
    const int g  = blockIdx.x & 3;       // row group 0..3
    const int r0 = g * RPB;

    const int tid = threadIdx.x;
    if (tid < CH * 3) w2s[tid] = w2[i * CH * 3 + tid];
    __syncthreads();

    const int wv = tid >> 6;             // local t4 row 0..15
    const int m  = tid & 63;             // column; 0..55 active

    // global t4 row index (wraps mod 56)
    const int n = (r0 - 2 + wv + NN) % NN;

    const bool actC = (m < NN);
    const bool actL = (m >= 1) && actC;
    const bool actH = (m + 1 < NN);

    // clamped (always in-bounds) addresses; invalid taps zeroed by select
    const int ml = actL ? (m - 1) : 0;
    const int mc = actC ? m       : 0;
    const int mh = actH ? (m + 1) : 0;

    const float* xrow = x + n * NN;

    float acc = 0.f;
    #pragma unroll 8
    for (int j = 0; j < CH; ++j) {
        const float* xr = xrow + j * XSTRIDE;
        float xl = xr[ml]; xl = actL ? xl : 0.f;
        float xc = xr[mc]; xc = actC ? xc : 0.f;
        float xh = xr[mh]; xh = actH ? xh : 0.f;
        acc = fmaf(xl, w2s[j*3+0], acc);
        acc = fmaf(xc, w2s[j*3+1], acc);
        acc = fmaf(xh, w2s[j*3+2], acc);
    }

    if (actC) t4s[wv][m] = acc;
    __syncthreads();

    // combine two adjacent t4 rows with w1 and store
    if (wv < RPB && actC) {
        const float a0 = w1[i*2+0];
        const float a1 = w1[i*2+1];
        const float v  = fmaf(a0, t4s[wv+1][m], a1 * t4s[wv][m]);
        out[i * XSTRIDE + (r0 + wv) * NN + m] = v;
    }
}

extern "C" void kernel_launch(void* const* d_in, const int* in_sizes, int n_in,
                              void* d_out, int out_size, void* d_ws, size_t ws_size,
                              hipStream_t stream) {
    const float* x  = (const float*)d_in[0];
    const float* w1 = (const float*)d_in[1];
    const float* w2 = (const float*)d_in[2];
    float* out      = (float*)d_out;

    dim3 grid(256);        // 64 channels x 4 row-groups  (1 block/CU)
    dim3 block(1024);      // 16 waves: one per t4 row
    hipLaunchKernelGGL(fused_shift_conv, grid, block, 0, stream, x, w1, w2, out);
}

// Round 2
// 62.595 us; speedup vs baseline: 1.0716x; 1.0716x over previous
//
#include <hip/hip_runtime.h>

#define CH 64
#define NN 56
#define XS (NN*NN)        // 3136 floats per channel image
#define RPB 7             // output rows per block
#define TR  8             // t4 rows per block (RPB + 1 extra for the two shifts)

// out[i,m,l] = g1[i,0]*t4[i,(m-1)%56,l] + g1[i,1]*t4[i,(m-2)%56,l]
// t4[i,n,l]  = sum_j sum_k g2[i,j,k] * x[j,n,l+k-1]   (zero-pad in l)
//
// Block = (channel i, group of 7 output rows). 256 threads = 8 row-slots x 32
// lanes; each lane owns a float2 of columns (28 active lanes cover 56 cols).
// Neighbor taps come from wave shuffles; edges masked by lane-constant selects.
// Weight reads are thread-uniform -> compiler emits scalar s_load (no VALU).
__global__ __launch_bounds__(256) void fused_shift_conv2(
    const float* __restrict__ x,
    const float* __restrict__ g1,
    const float* __restrict__ g2,
    float* __restrict__ out)
{
    __shared__ float t4s[TR][NN];

    const int i  = blockIdx.x >> 3;    // output channel 0..63
    const int g  = blockIdx.x & 7;     // row group 0..7
    const int r0 = g * RPB;

    const int tid = threadIdx.x;
    const int wv  = tid >> 5;          // row slot 0..7
    const int lr  = tid & 31;          // lane within row
    const int n   = (r0 - 2 + wv + NN) % NN;   // t4 row (wraps mod 56)

    const bool act = (lr < 28);
    const int  c   = (act ? lr : 27) * 2;      // clamped column base (even)

    const bool mL = (lr == 0);    // col 0 has no left tap
    const bool mH = (lr == 27);   // col 55 has no right tap

    const float* xp = x + n * NN + c;
    const float* wp = g2 + i * (CH * 3);       // uniform -> scalar loads

    float accx = 0.f, accy = 0.f;

    #pragma unroll 8
    for (int j = 0; j < CH; ++j) {
        float2 v = *(const float2*)(xp + j * XS);
        float xl = __shfl_up(v.y, 1);          // x[c-1] from lane-1
        float xh = __shfl_down(v.x, 1);        // x[c+2] from lane+1
        xl = mL ? 0.f : xl;
        xh = mH ? 0.f : xh;
        const float w0 = wp[3*j+0];
        const float w1 = wp[3*j+1];
        const float w2 = wp[3*j+2];
        accx = fmaf(xl,  w0, accx);
        accx = fmaf(v.x, w1, accx);
        accx = fmaf(v.y, w2, accx);
        accy = fmaf(v.x, w0, accy);
        accy = fmaf(v.y, w1, accy);
        accy = fmaf(xh,  w2, accy);
    }

    if (act) *(float2*)&t4s[wv][c] = make_float2(accx, accy);
    __syncthreads();

    if (wv < RPB && act) {
        const float a0 = g1[i*2+0];
        const float a1 = g1[i*2+1];
        const float2 tA = *(const float2*)&t4s[wv+1][c];  // t4 row r0+wv-1
        const float2 tB = *(const float2*)&t4s[wv][c];    // t4 row r0+wv-2
        float2 o;
        o.x = fmaf(a0, tA.x, a1 * tB.x);
        o.y = fmaf(a0, tA.y, a1 * tB.y);
        *(float2*)&out[i*XS + (r0 + wv)*NN + c] = o;
    }
}

extern "C" void kernel_launch(void* const* d_in, const int* in_sizes, int n_in,
                              void* d_out, int out_size, void* d_ws, size_t ws_size,
                              hipStream_t stream) {
    const float* x  = (const float*)d_in[0];
    const float* w1 = (const float*)d_in[1];
    const float* w2 = (const float*)d_in[2];
    float* out      = (float*)d_out;

    dim3 grid(64 * 8);     // 64 channels x 8 row-groups; 2 blocks/CU
    dim3 block(256);       // 8 row-slots x 32 lanes
    hipLaunchKernelGGL(fused_shift_conv2, grid, block, 0, stream, x, w1, w2, out);
}